// Round 6
// baseline (340.975 us; speedup 1.0000x reference)
//
#include <hip/hip_runtime.h>
#include <cstdint>
#include <cstddef>

#define CH 64
#define NP 65536          // F*S
constexpr float EPS_LN = 1e-5f;

using f32x4  = __attribute__((ext_vector_type(4))) float;
using bf16x8 = __attribute__((ext_vector_type(8))) short;
using s16x4  = __attribute__((ext_vector_type(4))) short;

__device__ __forceinline__ short f2bf(float f){
  union { float f; uint32_t u; } v; v.f = f;
  uint32_t r = v.u + 0x7FFFu + ((v.u >> 16) & 1u);
  return (short)(r >> 16);
}
__device__ __forceinline__ float bf2f(short s){
  union { uint32_t u; float f; } v; v.u = ((uint32_t)(uint16_t)s) << 16;
  return v.f;
}
__device__ __forceinline__ float sigmoidf_(float x){ return 1.f/(1.f+__expf(-x)); }

// LDS-only barrier: waits lgkmcnt(0) but leaves vmcnt (global prefetch) in flight.
__device__ __forceinline__ void lds_barrier(){
  asm volatile("s_waitcnt lgkmcnt(0)\n\ts_barrier" ::: "memory");
}
// Wave-level fence: orders this wave's LDS writes before its subsequent LDS reads.
// No cross-wave sync — wave-private scratch only.
__device__ __forceinline__ void wave_fence(){
  asm volatile("s_waitcnt lgkmcnt(0)" ::: "memory");
}

// ---------------- prep: x stats partials (1024 blks) + bf16 weight conversion ----------------
__global__ __launch_bounds__(256) void k_prep(
    const float* __restrict__ x,
    const float* __restrict__ w1, const float* __restrict__ w2,
    const float* __restrict__ w3, const float* __restrict__ w4,
    float* __restrict__ xstat, short* __restrict__ wbf)
{
  int blk = blockIdx.x, tid = threadIdx.x;
  if (blk < 1024) {
    int b = blk >> 8, chunk = blk & 255;
    const float* base = x + (size_t)b*CH*NP + (size_t)chunk*16384;
    float s = 0.f, s2 = 0.f;
    for (int i = tid*4; i < 16384; i += 1024) {
      f32x4 v = *(const f32x4*)(base + i);
      s  += v.x + v.y + v.z + v.w;
      s2 += v.x*v.x + v.y*v.y + v.z*v.z + v.w*v.w;
    }
    for (int d=1; d<64; d<<=1){ s += __shfl_xor(s,d,64); s2 += __shfl_xor(s2,d,64); }
    __shared__ float ls[8];
    int wv = tid>>6;
    if ((tid&63)==0){ ls[wv]=s; ls[4+wv]=s2; }
    __syncthreads();
    if (tid==0){
      xstat[blk*2]   = ls[0]+ls[1]+ls[2]+ls[3];
      xstat[blk*2+1] = ls[4]+ls[5]+ls[6]+ls[7];
    }
  } else {
    int wblk = blk - 1024;  // 24 blocks x 1024 elems
    const float* src; short* dst; int off;
    if (wblk < 8)       { src = w1; dst = wbf;         off = wblk*1024; }
    else if (wblk < 12) { src = w2; dst = wbf + 8192;  off = (wblk-8)*1024; }
    else if (wblk < 20) { src = w3; dst = wbf + 12288; off = (wblk-12)*1024; }
    else                { src = w4; dst = wbf + 20480; off = (wblk-20)*1024; }
    for (int i = tid; i < 1024; i += 256) dst[off+i] = f2bf(src[off+i]);
  }
}

__global__ void k_fin1(const float* __restrict__ xstat, float* __restrict__ stats1){
  int b = threadIdx.x >> 6, lane = threadIdx.x & 63;
  float s=0.f, s2=0.f;
  #pragma unroll
  for (int j=0;j<4;j++){
    int i = b*256 + j*64 + lane;
    s += xstat[i*2]; s2 += xstat[i*2+1];
  }
  for (int d=1; d<64; d<<=1){ s += __shfl_xor(s,d,64); s2 += __shfl_xor(s2,d,64); }
  if (lane==0){
    float m = s*(1.f/4194304.f);
    float v = s2*(1.f/4194304.f) - m*m;
    stats1[b]=m; stats1[4+b]=rsqrtf(v+EPS_LN);
  }
}

// ---------------- branch1: LN1 + GEMM w1(*dww) + GLU -> hglu[pos][c] + pool partial ----------------
// Wave-private pipeline: each wave owns 64 consecutive pos (4 iters x 16).
// Barriers only for weight staging (start) and pool reduction (end).
__global__ __launch_bounds__(256,4) void k_branch1(
    const float* __restrict__ x, const float* __restrict__ lnw, const float* __restrict__ lnb,
    const short* __restrict__ w1bf, const float* __restrict__ b1,
    const float* __restrict__ dww, const float* __restrict__ dwb,
    const float* __restrict__ stats1, short* __restrict__ hglu, float* __restrict__ ppart)
{
  int blk = blockIdx.x;                 // 1024
  int b = blk >> 8;
  int tid = threadIdx.x, wv = tid>>6, lane = tid&63, l = lane&15, q = lane>>4;
  int base = (blk & 255)*256 + wv*64;   // wave's 64-pos strip
  float mean = stats1[b], rstd = stats1[4+b];
  const float* xb = x + (size_t)b*CH*NP;
  short* hb = hglu + (size_t)b*CH*NP;   // [pos][c]

  __shared__ __align__(16) short wlds[8192];    // w1*dww, fragment-linear (block-shared)
  __shared__ __align__(16) float cc[128];       // b1*dww + dwb
  __shared__ float pacc[4][64];
  __shared__ __align__(16) short linS[4][1280]; // per-wave [c][pos16], stride 20 shorts
  short* lin = linS[wv];

  #pragma unroll
  for (int g0=0; g0<4; g0++){
    int g = g0*256 + tid;
    int mt = g>>7, ks = (g>>6)&1, qq = (g>>4)&3, ll = g&15;
    int m = mt*16 + ll;
    float sc = dww[m];
    bf16x8 w8 = *(const bf16x8*)(w1bf + (m*CH + ks*32 + qq*8));
    #pragma unroll
    for (int j=0;j<8;j++) w8[j] = f2bf(bf2f(w8[j]) * sc);
    *(bf16x8*)(&wlds[g*8]) = w8;
  }
  if (tid < 128) cc[tid] = b1[tid]*dww[tid] + dwb[tid];

  // prefetch iter-0 x (lane: c = it*16+l, pos = base + q*4..+3)
  f32x4 pX[4];
  #pragma unroll
  for (int it=0; it<4; it++)
    pX[it] = *(const f32x4*)(xb + (size_t)(it*16+l)*NP + base + q*4);
  lds_barrier();   // wlds/cc visible; pX in flight

  float rsum[16];
  #pragma unroll
  for (int i=0;i<16;i++) rsum[i]=0.f;

  #pragma unroll
  for (int t=0; t<4; t++){
    int pos_w = base + t*16;
    // LN -> lin (wave-private); lnw/lnb loaded inline
    #pragma unroll
    for (int it=0; it<4; it++){
      int c = it*16 + l;
      size_t o = (size_t)c*NP + pos_w + q*4;
      f32x4 lw4 = *(const f32x4*)(lnw + o);
      f32x4 lb4 = *(const f32x4*)(lnb + o);
      s16x4 pk;
      #pragma unroll
      for (int j=0;j<4;j++) pk[j] = f2bf((pX[it][j]-mean)*rstd*lw4[j] + lb4[j]);
      *(s16x4*)(&lin[c*20 + q*4]) = pk;
    }
    if (t < 3){
      #pragma unroll
      for (int it=0; it<4; it++)
        pX[it] = *(const f32x4*)(xb + (size_t)(it*16+l)*NP + pos_w + 16 + q*4);
    }
    wave_fence();  // lin writes -> bfrag reads (same wave)

    bf16x8 bfrag[2];
    #pragma unroll
    for (int ks=0; ks<2; ks++)
      #pragma unroll
      for (int j=0; j<8; j++)
        bfrag[ks][j] = lin[(ks*32 + q*8 + j)*20 + l];

    f32x4 acc[8];
    #pragma unroll
    for (int mt=0; mt<8; mt++){
      f32x4 a = {0.f,0.f,0.f,0.f};
      #pragma unroll
      for (int ks=0; ks<2; ks++){
        bf16x8 af = *(const bf16x8*)(&wlds[(mt*128 + ks*64 + q*16 + l)*8]);
        a = __builtin_amdgcn_mfma_f32_16x16x32_bf16(af, bfrag[ks], a, 0, 0, 0);
      }
      acc[mt] = a;
    }

    // GLU -> hglu store (C-layout: lane holds c=mt*16+q*4+r at pos = pos_w + l)
    #pragma unroll
    for (int mt=0; mt<4; mt++){
      f32x4 ccA = *(const f32x4*)(&cc[mt*16 + q*4]);
      f32x4 ccG = *(const f32x4*)(&cc[64 + mt*16 + q*4]);
      s16x4 pk;
      #pragma unroll
      for (int r=0; r<4; r++){
        float av = acc[mt][r]   + ccA[r];
        float gv = acc[mt+4][r] + ccG[r];
        float h = av * sigmoidf_(gv);
        rsum[mt*4+r] += h;
        pk[r] = f2bf(h);
      }
      *(s16x4*)(hb + (size_t)(pos_w + l)*CH + mt*16 + q*4) = pk;
    }
    // next iter's lin writes follow this iter's bfrag reads in wave program order — safe
  }

  // pool partials: reduce over l (16 pos) within each quad, then across waves
  #pragma unroll
  for (int i=0;i<16;i++){
    float v = rsum[i];
    v += __shfl_xor(v,1,64); v += __shfl_xor(v,2,64);
    v += __shfl_xor(v,4,64); v += __shfl_xor(v,8,64);
    if (l==0) pacc[wv][(i>>2)*16 + q*4 + (i&3)] = v;
  }
  __syncthreads();
  if (tid < 64){
    float s = pacc[0][tid]+pacc[1][tid]+pacc[2][tid]+pacc[3][tid];
    ppart[((size_t)b*256 + (blk & 255))*64 + tid] = s;
  }
}

// ---------------- channel attention MLP + fold s into w2 -> w2s[b] (bf16) ----------------
__global__ __launch_bounds__(1024) void k_attn(
    const float* __restrict__ ppart,
    const float* __restrict__ aw1, const float* __restrict__ ab1,
    const float* __restrict__ aw2, const float* __restrict__ ab2,
    const short* __restrict__ w2bf, short* __restrict__ w2s)
{
  int b = blockIdx.x, t = threadIdx.x;
  int c = t & 63, seg = t >> 6;        // seg 0..15
  __shared__ float awl1[64*65], awl2[64*65];
  __shared__ float pl[16][64];
  __shared__ float parr[64], t1a[64], sarr[64];

  #pragma unroll
  for (int k=0;k<4;k++){
    int i = t + k*1024;
    int row = i >> 6, col = i & 63;
    awl1[row*65 + col] = aw1[i];
    awl2[row*65 + col] = aw2[i];
  }
  const float* pb = ppart + (size_t)b*256*64;
  float s = 0.f;
  #pragma unroll
  for (int k=0;k<16;k++) s += pb[(seg*16 + k)*64 + c];
  pl[seg][c] = s;
  __syncthreads();
  if (t < 64){
    float acc = 0.f;
    #pragma unroll
    for (int j=0;j<16;j++) acc += pl[j][t];
    parr[t] = acc * (1.f/65536.f);
  }
  __syncthreads();
  if (t < 64){
    float acc = ab1[t];
    #pragma unroll
    for (int k=0;k<64;k++) acc += awl1[t*65+k]*parr[k];
    t1a[t] = fmaxf(acc, 0.f);
  }
  __syncthreads();
  if (t < 64){
    float acc = ab2[t];
    #pragma unroll
    for (int k=0;k<64;k++) acc += awl2[t*65+k]*t1a[k];
    sarr[t] = sigmoidf_(acc);
  }
  __syncthreads();
  #pragma unroll
  for (int k=0;k<4;k++){
    int i = t + k*1024;
    w2s[b*4096 + i] = f2bf(bf2f(w2bf[i]) * sarr[i & 63]);
  }
}

// ---------------- mid: GEMM w2s + b2 + x -> y (d_out) + y stats partials ----------------
// Wave-private; zero steady-state barriers.
__global__ __launch_bounds__(256,4) void k_mid(
    const short* __restrict__ hglu, const short* __restrict__ w2s,
    const float* __restrict__ b2, const float* __restrict__ x,
    float* __restrict__ y, float* __restrict__ ystat)
{
  int blk = blockIdx.x;                 // 1024
  int b = blk >> 8;
  int tid = threadIdx.x, wv = tid>>6, lane = tid&63, l = lane&15, q = lane>>4;
  int base = (blk & 255)*256 + wv*64;
  const short* hb = hglu + (size_t)b*CH*NP;
  const float* xb = x + (size_t)b*CH*NP;
  float* yb = y + (size_t)b*CH*NP;

  __shared__ __align__(16) short w2l[4096];
  __shared__ __align__(16) float foutS[4][1088];  // per-wave [pos16][c], stride 68 dwords
  float* fout = foutS[wv];

  #pragma unroll
  for (int g0=0; g0<2; g0++){
    int g = g0*256 + tid;
    int mt = g>>7, ks = (g>>6)&1, qq = (g>>4)&3, ll = g&15;
    *(bf16x8*)(&w2l[g*8]) = *(const bf16x8*)(w2s + b*4096 + (mt*16+ll)*CH + ks*32 + qq*8);
  }
  float b2v[4];
  #pragma unroll
  for (int it=0; it<4; it++) b2v[it] = b2[it*16 + l];

  // prefetch iter-0
  bf16x8 pH0, pH1; f32x4 pX[4];
  {
    const short* hr = hb + (size_t)(base + l)*CH;
    pH0 = *(const bf16x8*)(hr + q*8);
    pH1 = *(const bf16x8*)(hr + 32 + q*8);
    #pragma unroll
    for (int it=0; it<4; it++)
      pX[it] = *(const f32x4*)(xb + (size_t)(it*16+l)*NP + base + q*4);
  }
  lds_barrier();   // w2l visible (staged by all threads); prefetch in flight

  float s1=0.f, s2=0.f;
  #pragma unroll
  for (int t=0; t<4; t++){
    int pos_w = base + t*16;
    bf16x8 h0 = pH0, h1 = pH1;
    if (t < 3){
      const short* hr = hb + (size_t)(pos_w + 16 + l)*CH;
      pH0 = *(const bf16x8*)(hr + q*8);
      pH1 = *(const bf16x8*)(hr + 32 + q*8);
    }
    f32x4 acc[4];
    #pragma unroll
    for (int mt=0; mt<4; mt++){
      f32x4 a = {0.f,0.f,0.f,0.f};
      a = __builtin_amdgcn_mfma_f32_16x16x32_bf16(
            *(const bf16x8*)(&w2l[(mt*128 + 0*64 + q*16 + l)*8]), h0, a, 0,0,0);
      a = __builtin_amdgcn_mfma_f32_16x16x32_bf16(
            *(const bf16x8*)(&w2l[(mt*128 + 1*64 + q*16 + l)*8]), h1, a, 0,0,0);
      acc[mt] = a;
    }
    #pragma unroll
    for (int mt=0; mt<4; mt++)
      *(f32x4*)(&fout[l*68 + mt*16 + q*4]) = acc[mt];
    wave_fence();  // fout writes -> transposed reads (same wave)

    f32x4 yv[4];
    #pragma unroll
    for (int it=0; it<4; it++){
      int c = it*16 + l;
      #pragma unroll
      for (int j=0;j<4;j++){
        float v = fout[(q*4+j)*68 + c] + b2v[it] + pX[it][j];
        yv[it][j] = v; s1 += v; s2 += v*v;
      }
    }
    if (t < 3){
      #pragma unroll
      for (int it=0; it<4; it++)
        pX[it] = *(const f32x4*)(xb + (size_t)(it*16+l)*NP + pos_w + 16 + q*4);
    }
    #pragma unroll
    for (int it=0; it<4; it++)
      *(f32x4*)(yb + (size_t)(it*16+l)*NP + pos_w + q*4) = yv[it];
    // next iter's fout writes follow this iter's reads in wave program order — safe
  }

  for (int d=1; d<64; d<<=1){ s1 += __shfl_xor(s1,d,64); s2 += __shfl_xor(s2,d,64); }
  __shared__ float red[8];
  if (lane==0){ red[wv]=s1; red[4+wv]=s2; }
  __syncthreads();
  if (tid==0){
    ystat[(size_t)blk*2]   = red[0]+red[1]+red[2]+red[3];
    ystat[(size_t)blk*2+1] = red[4]+red[5]+red[6]+red[7];
  }
}

__global__ void k_fin2(const float* __restrict__ ystat, float* __restrict__ stats2){
  int t = threadIdx.x;           // 256
  int b = t >> 6, lane = t & 63;
  float s=0.f, s2=0.f;
  #pragma unroll
  for (int j=0;j<4;j++){
    int e = b*256 + j*64 + lane;
    s  += ystat[e*2];
    s2 += ystat[e*2+1];
  }
  for (int d=1; d<64; d<<=1){ s += __shfl_xor(s,d,64); s2 += __shfl_xor(s2,d,64); }
  if (lane==0){
    float m = s*(1.f/4194304.f);
    float v = s2*(1.f/4194304.f) - m*m;
    stats2[b]=m; stats2[4+b]=rsqrtf(v+EPS_LN);
  }
}

// ---------------- branch2: LN2 + GEMM w3 + GLU + GEMM w4 + residual (in-place over y) ----------------
// Wave-private; per-wave union region lin/glu/fout; 2 iters x 16 pos per wave.
__global__ __launch_bounds__(256,3) void k_branch2(
    float* __restrict__ yio, const float* __restrict__ lnw, const float* __restrict__ lnb,
    const short* __restrict__ w3bf, const float* __restrict__ b3,
    const short* __restrict__ w4bf, const float* __restrict__ b4,
    const float* __restrict__ stats2)
{
  int blk = blockIdx.x;                 // 2048
  int b = blk >> 9;
  int tid = threadIdx.x, wv = tid>>6, lane = tid&63, l = lane&15, q = lane>>4;
  int base = (blk & 511)*128 + wv*32;   // wave's 32-pos strip
  float mean = stats2[b], rstd = stats2[4+b];
  float* yb = yio + (size_t)b*CH*NP;

  __shared__ __align__(16) short w3l[8192];
  __shared__ __align__(16) short w4l[4096];
  __shared__ __align__(16) float b3l[128];
  __shared__ __align__(16) char uniS[4][4352];  // per-wave: lin(2560B) / glu(2560B) / fout(4352B)
  short* lin  = (short*)uniS[wv];   // [c][pos16] stride 20 shorts
  short* glu  = (short*)uniS[wv];   // [pos16][c] stride 80 shorts
  float* fout = (float*)uniS[wv];   // [pos16][c] stride 68 dwords

  #pragma unroll
  for (int g0=0; g0<4; g0++){
    int g = g0*256 + tid;
    int mt = g>>7, ks = (g>>6)&1, qq = (g>>4)&3, ll = g&15;
    *(bf16x8*)(&w3l[g*8]) = *(const bf16x8*)(w3bf + ((mt*16+ll)*CH + ks*32 + qq*8));
  }
  #pragma unroll
  for (int g0=0; g0<2; g0++){
    int g = g0*256 + tid;
    int mt = g>>7, ks = (g>>6)&1, qq = (g>>4)&3, ll = g&15;
    *(bf16x8*)(&w4l[g*8]) = *(const bf16x8*)(w4bf + ((mt*16+ll)*CH + ks*32 + qq*8));
  }
  if (tid < 128) b3l[tid] = b3[tid];
  float b4v[4];
  #pragma unroll
  for (int it=0; it<4; it++) b4v[it] = b4[it*16 + l];

  // prefetch iter-0 y (persists for residual)
  f32x4 pY[4];
  #pragma unroll
  for (int it=0; it<4; it++)
    pY[it] = *(const f32x4*)(yb + (size_t)(it*16+l)*NP + base + q*4);
  lds_barrier();   // w3l/w4l/b3l visible; pY in flight

  #pragma unroll
  for (int t=0; t<2; t++){
    int pos_w = base + t*16;
    // LN -> lin (lnw/lnb inline)
    #pragma unroll
    for (int it=0; it<4; it++){
      int c = it*16 + l;
      size_t o = (size_t)c*NP + pos_w + q*4;
      f32x4 lw4 = *(const f32x4*)(lnw + o);
      f32x4 lb4 = *(const f32x4*)(lnb + o);
      s16x4 pk;
      #pragma unroll
      for (int j=0;j<4;j++) pk[j] = f2bf((pY[it][j]-mean)*rstd*lw4[j] + lb4[j]);
      *(s16x4*)(&lin[c*20 + q*4]) = pk;
    }
    f32x4 nY[4];
    if (t < 1){
      #pragma unroll
      for (int it=0; it<4; it++)
        nY[it] = *(const f32x4*)(yb + (size_t)(it*16+l)*NP + pos_w + 16 + q*4);
    }
    wave_fence();  // lin writes -> bfrag reads

    bf16x8 bfrag[2];
    #pragma unroll
    for (int ks=0; ks<2; ks++)
      #pragma unroll
      for (int j=0; j<8; j++)
        bfrag[ks][j] = lin[(ks*32 + q*8 + j)*20 + l];

    f32x4 acc[8];
    #pragma unroll
    for (int mt=0; mt<8; mt++){
      f32x4 a = {0.f,0.f,0.f,0.f};
      #pragma unroll
      for (int ks=0; ks<2; ks++){
        bf16x8 af = *(const bf16x8*)(&w3l[(mt*128 + ks*64 + q*16 + l)*8]);
        a = __builtin_amdgcn_mfma_f32_16x16x32_bf16(af, bfrag[ks], a, 0, 0, 0);
      }
      acc[mt] = a;
    }

    // GLU -> glu scratch (overwrites lin; data-dep on acc keeps it after bfrag reads)
    #pragma unroll
    for (int mt=0; mt<4; mt++){
      f32x4 bA = *(const f32x4*)(&b3l[mt*16 + q*4]);
      f32x4 bG = *(const f32x4*)(&b3l[64 + mt*16 + q*4]);
      s16x4 pk;
      #pragma unroll
      for (int r=0; r<4; r++){
        float av = acc[mt][r]   + bA[r];
        float gv = acc[mt+4][r] + bG[r];
        pk[r] = f2bf(av * sigmoidf_(gv));
      }
      *(s16x4*)(&glu[l*80 + mt*16 + q*4]) = pk;
    }
    wave_fence();  // glu writes -> pfrag reads

    bf16x8 pfrag[2];
    pfrag[0] = *(const bf16x8*)(&glu[l*80 + q*8]);
    pfrag[1] = *(const bf16x8*)(&glu[l*80 + 32 + q*8]);

    f32x4 acc2[4];
    #pragma unroll
    for (int mt=0; mt<4; mt++){
      f32x4 a = {0.f,0.f,0.f,0.f};
      #pragma unroll
      for (int ks=0; ks<2; ks++){
        bf16x8 af = *(const bf16x8*)(&w4l[(mt*128 + ks*64 + q*16 + l)*8]);
        a = __builtin_amdgcn_mfma_f32_16x16x32_bf16(af, ks ? pfrag[1] : pfrag[0], a, 0, 0, 0);
      }
      acc2[mt] = a;
    }
    // C -> fout (overwrites glu; data-dep on acc2 keeps it after pfrag reads)
    #pragma unroll
    for (int mt=0; mt<4; mt++)
      *(f32x4*)(&fout[l*68 + mt*16 + q*4]) = acc2[mt];
    wave_fence();  // fout writes -> transposed reads

    f32x4 yv[4];
    #pragma unroll
    for (int it=0; it<4; it++){
      int c = it*16 + l;
      #pragma unroll
      for (int j=0;j<4;j++)
        yv[it][j] = fout[(q*4+j)*68 + c] + b4v[it] + pY[it][j];
    }
    #pragma unroll
    for (int it=0; it<4; it++)
      *(f32x4*)(yb + (size_t)(it*16+l)*NP + pos_w + q*4) = yv[it];
    if (t < 1){
      #pragma unroll
      for (int it=0; it<4; it++) pY[it] = nY[it];
    }
    // next iter's lin writes follow this iter's fout reads in wave program order — safe
  }
}

extern "C" void kernel_launch(void* const* d_in, const int* in_sizes, int n_in,
                              void* d_out, int out_size, void* d_ws, size_t ws_size,
                              hipStream_t stream){
  const float* x    = (const float*)d_in[0];
  const float* ln1w = (const float*)d_in[1];
  const float* ln1b = (const float*)d_in[2];
  const float* ln2w = (const float*)d_in[3];
  const float* ln2b = (const float*)d_in[4];
  const float* w1   = (const float*)d_in[5];
  const float* b1   = (const float*)d_in[6];
  const float* dww  = (const float*)d_in[7];
  const float* dwb  = (const float*)d_in[8];
  const float* aw1  = (const float*)d_in[9];
  const float* ab1  = (const float*)d_in[10];
  const float* aw2  = (const float*)d_in[11];
  const float* ab2  = (const float*)d_in[12];
  const float* w2   = (const float*)d_in[13];
  const float* b2   = (const float*)d_in[14];
  const float* w3   = (const float*)d_in[15];
  const float* b3   = (const float*)d_in[16];
  const float* w4   = (const float*)d_in[17];
  const float* b4   = (const float*)d_in[18];
  float* out = (float*)d_out;
  float* ws  = (float*)d_ws;

  // ws layout (float offsets)
  float* xstat  = ws;                     // 2048
  float* stats1 = ws + 2048;              // 8
  float* ystat  = ws + 2112;              // 2048
  float* stats2 = ws + 10304;             // 8
  short* wbf    = (short*)(ws + 10368);   // 24576 bf16: w1|w2|w3|w4
  short* w2s    = (short*)(ws + 22656);   // 16384 bf16: per-batch scaled w2
  float* ppart  = ws + 30848;             // 65536 (pre-reduced [4][256][64])
  short* hglu   = (short*)(ws + 292992);  // 16777216 bf16 [b][pos][c]; total ~34.7 MB

  hipLaunchKernelGGL(k_prep,    dim3(1048), dim3(256),  0, stream, x, w1, w2, w3, w4, xstat, wbf);
  hipLaunchKernelGGL(k_fin1,    dim3(1),    dim3(256),  0, stream, xstat, stats1);
  hipLaunchKernelGGL(k_branch1, dim3(1024), dim3(256),  0, stream, x, ln1w, ln1b, wbf, b1, dww, dwb, stats1, hglu, ppart);
  hipLaunchKernelGGL(k_attn,    dim3(4),    dim3(1024), 0, stream, ppart, aw1, ab1, aw2, ab2, wbf + 8192, w2s);
  hipLaunchKernelGGL(k_mid,     dim3(1024), dim3(256),  0, stream, hglu, w2s, b2, x, out, ystat);
  hipLaunchKernelGGL(k_fin2,    dim3(1),    dim3(256),  0, stream, ystat, stats2);
  hipLaunchKernelGGL(k_branch2, dim3(2048), dim3(256),  0, stream, out, ln2w, ln2b, wbf + 12288, b3, wbf + 20480, b4, stats2);
}